// Round 1
// baseline (189.131 us; speedup 1.0000x reference)
//
#include <hip/hip_runtime.h>
#include <math.h>

// StatefulRosenberg: segmented cumsum (16 rows x 1,048,576) + Rosenberg pulse.
// fp64 accumulation for the phase (np-ref f32 serial cumsum noise ~3e-4 >> our error).

constexpr int BATCH   = 16;
constexpr int T       = 1048576;
constexpr int THREADS = 256;
constexpr int VPT     = 16;               // elements per thread
constexpr int CHUNK   = THREADS * VPT;    // 4096
constexpr int NCHUNK  = T / CHUNK;        // 256

#define PI_F 3.14159265358979323846f

// ---------------- Pass 1: per-chunk fp64 sums ----------------
__global__ __launch_bounds__(THREADS) void k_chunk_sums(
    const float* __restrict__ f0, double* __restrict__ partial)
{
    const int chunk = blockIdx.x;
    const int row   = blockIdx.y;
    const float* base = f0 + (size_t)row * T + (size_t)chunk * CHUNK
                           + (size_t)threadIdx.x * VPT;
    double s = 0.0;
#pragma unroll
    for (int j = 0; j < VPT / 4; ++j) {
        float4 v = ((const float4*)base)[j];
        s += (double)(v.x / 48000.0f);
        s += (double)(v.y / 48000.0f);
        s += (double)(v.z / 48000.0f);
        s += (double)(v.w / 48000.0f);
    }
    // wave64 reduce
#pragma unroll
    for (int off = 32; off > 0; off >>= 1)
        s += __shfl_down(s, off, 64);
    __shared__ double ws[THREADS / 64];
    const int lane = threadIdx.x & 63, wid = threadIdx.x >> 6;
    if (lane == 0) ws[wid] = s;
    __syncthreads();
    if (threadIdx.x == 0) {
        double tot = 0.0;
#pragma unroll
        for (int w = 0; w < THREADS / 64; ++w) tot += ws[w];
        partial[row * NCHUNK + chunk] = tot;
    }
}

// ---------------- Pass 2: per-row sequential scan of chunk sums ----------------
__global__ void k_row_scan(const double* __restrict__ partial,
                           const float* __restrict__ phase_state,
                           double* __restrict__ chunk_off,
                           float* __restrict__ next_state)
{
    const int row = blockIdx.x;
    if (threadIdx.x != 0) return;
    double acc = (double)phase_state[row];
    const double* p = partial + row * NCHUNK;
    double* o = chunk_off + row * NCHUNK;
    for (int i = 0; i < NCHUNK; ++i) { o[i] = acc; acc += p[i]; }
    next_state[row] = (float)acc;   // unwrapped final phase (incl. phase_state)
}

// ---------------- Pass 3: intra-chunk scan + Rosenberg pulse ----------------
__global__ __launch_bounds__(THREADS) void k_emit(
    const float* __restrict__ f0, const float* __restrict__ oq,
    const double* __restrict__ chunk_off, float* __restrict__ wav)
{
    const int chunk = blockIdx.x;
    const int row   = blockIdx.y;
    const size_t base_idx = (size_t)row * T + (size_t)chunk * CHUNK
                          + (size_t)threadIdx.x * VPT;

    // load f0, compute f32 steps (matches ref rounding) + thread fp64 sum
    float st[VPT];
    double tsum = 0.0;
    {
        const float4* fb = (const float4*)(f0 + base_idx);
#pragma unroll
        for (int j = 0; j < VPT / 4; ++j) {
            float4 v = fb[j];
            st[4 * j + 0] = v.x / 48000.0f;
            st[4 * j + 1] = v.y / 48000.0f;
            st[4 * j + 2] = v.z / 48000.0f;
            st[4 * j + 3] = v.w / 48000.0f;
        }
#pragma unroll
        for (int i = 0; i < VPT; ++i) tsum += (double)st[i];
    }

    // block exclusive scan of per-thread sums (wave shfl scan + cross-wave LDS)
    const int lane = threadIdx.x & 63, wid = threadIdx.x >> 6;
    double inc = tsum;
#pragma unroll
    for (int off = 1; off < 64; off <<= 1) {
        double n = __shfl_up(inc, off, 64);
        if (lane >= off) inc += n;
    }
    __shared__ double ws[THREADS / 64];
    if (lane == 63) ws[wid] = inc;
    __syncthreads();
    double run = chunk_off[row * NCHUNK + chunk] + (inc - tsum);
#pragma unroll
    for (int w = 0; w < THREADS / 64; ++w)
        if (w < wid) run += ws[w];

    // load oq
    float o[VPT];
    {
        const float4* ob = (const float4*)(oq + base_idx);
#pragma unroll
        for (int j = 0; j < VPT / 4; ++j) {
            float4 v = ob[j];
            o[4 * j + 0] = v.x; o[4 * j + 1] = v.y;
            o[4 * j + 2] = v.z; o[4 * j + 3] = v.w;
        }
    }

    // sequential accumulate + pulse; one cosf per element via arg-select
    float outv[VPT];
#pragma unroll
    for (int i = 0; i < VPT; ++i) {
        run += (double)st[i];
        float ph  = (float)(run - floor(run));     // wrapped phase in [0,1)
        float oqv = o[i];
        float tp  = oqv * 0.66f;
        float tn  = oqv - tp;
        bool  is_rise = ph < tp;
        bool  in_pulse = ph < oqv;                 // rise or fall region
        float arg = is_rise ? (PI_F * ph) / (tp + 1e-6f)
                            : (PI_F * (ph - tp)) / (2.0f * tn + 1e-6f);
        float c = cosf(arg);
        float w = is_rise ? 0.5f * (1.0f - c) : (in_pulse ? c : 0.0f);
        outv[i] = w;
    }

    float4* wb = (float4*)(wav + base_idx);
#pragma unroll
    for (int j = 0; j < VPT / 4; ++j) {
        wb[j] = make_float4(outv[4 * j + 0], outv[4 * j + 1],
                            outv[4 * j + 2], outv[4 * j + 3]);
    }
}

extern "C" void kernel_launch(void* const* d_in, const int* in_sizes, int n_in,
                              void* d_out, int out_size, void* d_ws, size_t ws_size,
                              hipStream_t stream)
{
    const float* f0          = (const float*)d_in[0];
    const float* oq          = (const float*)d_in[1];
    const float* phase_state = (const float*)d_in[2];
    float* out = (float*)d_out;                 // [B*T] wav, then [B] next_state

    double* partial   = (double*)d_ws;                  // B*NCHUNK doubles
    double* chunk_off = partial + (size_t)BATCH * NCHUNK;

    dim3 grid(NCHUNK, BATCH);
    k_chunk_sums<<<grid, THREADS, 0, stream>>>(f0, partial);
    k_row_scan<<<BATCH, 64, 0, stream>>>(partial, phase_state, chunk_off,
                                         out + (size_t)BATCH * T);
    k_emit<<<grid, THREADS, 0, stream>>>(f0, oq, chunk_off, out);
}

// Round 2
// 182.347 us; speedup vs baseline: 1.0372x; 1.0372x over previous
//
#include <hip/hip_runtime.h>
#include <math.h>

// StatefulRosenberg: segmented cumsum (16 rows x 1,048,576) + Rosenberg pulse.
// fp64 phase accumulation (np-ref serial f32 cumsum noise ~3e-4 >> our error).
// R1->R2: removed serial k_row_scan (prefix folded into k_emit as a parallel
// reduce over L2-hot partials); cosf -> v_cos_f32 in revolutions; div -> rcp/mul.

constexpr int BATCH   = 16;
constexpr int T       = 1048576;
constexpr int THREADS = 256;
constexpr int VPT     = 16;               // elements per thread
constexpr int CHUNK   = THREADS * VPT;    // 4096
constexpr int NCHUNK  = T / CHUNK;        // 256

#define INV_SR (1.0f / 48000.0f)

// ---------------- Pass 1: per-chunk fp64 sums ----------------
__global__ __launch_bounds__(THREADS) void k_chunk_sums(
    const float* __restrict__ f0, double* __restrict__ partial)
{
    const int chunk = blockIdx.x;
    const int row   = blockIdx.y;
    const float4* base = (const float4*)(f0 + (size_t)row * T
                       + (size_t)chunk * CHUNK + (size_t)threadIdx.x * VPT);
    double s = 0.0;
#pragma unroll
    for (int j = 0; j < VPT / 4; ++j) {
        float4 v = base[j];
        s += (double)(v.x * INV_SR);
        s += (double)(v.y * INV_SR);
        s += (double)(v.z * INV_SR);
        s += (double)(v.w * INV_SR);
    }
#pragma unroll
    for (int off = 32; off > 0; off >>= 1)
        s += __shfl_down(s, off, 64);
    __shared__ double ws[THREADS / 64];
    const int lane = threadIdx.x & 63, wid = threadIdx.x >> 6;
    if (lane == 0) ws[wid] = s;
    __syncthreads();
    if (threadIdx.x == 0) {
        double tot = 0.0;
#pragma unroll
        for (int w = 0; w < THREADS / 64; ++w) tot += ws[w];
        partial[row * NCHUNK + chunk] = tot;
    }
}

// ---------------- Pass 2: prefix + intra-chunk scan + Rosenberg pulse ----------------
__global__ __launch_bounds__(THREADS) void k_emit(
    const float* __restrict__ f0, const float* __restrict__ oq,
    const double* __restrict__ partial, const float* __restrict__ phase_state,
    float* __restrict__ wav, float* __restrict__ next_state)
{
    const int chunk = blockIdx.x;
    const int row   = blockIdx.y;
    const int lane  = threadIdx.x & 63, wid = threadIdx.x >> 6;
    const size_t base_idx = (size_t)row * T + (size_t)chunk * CHUNK
                          + (size_t)threadIdx.x * VPT;

    __shared__ double rs[THREADS / 64];   // chunk-prefix partial reduce
    __shared__ double ws[THREADS / 64];   // wave inclusive totals

    // ---- chunk prefix: parallel reduce of partial[row][0..chunk-1] (2 KB, L2-hot)
    double pv = (threadIdx.x < chunk) ? partial[row * NCHUNK + threadIdx.x] : 0.0;
#pragma unroll
    for (int off = 32; off > 0; off >>= 1)
        pv += __shfl_down(pv, off, 64);
    if (lane == 0) rs[wid] = pv;

    // ---- load f0, f32 steps (match ref rounding scale) + thread fp64 sum
    float st[VPT];
    double tsum = 0.0;
    {
        const float4* fb = (const float4*)(f0 + base_idx);
#pragma unroll
        for (int j = 0; j < VPT / 4; ++j) {
            float4 v = fb[j];
            st[4 * j + 0] = v.x * INV_SR;
            st[4 * j + 1] = v.y * INV_SR;
            st[4 * j + 2] = v.z * INV_SR;
            st[4 * j + 3] = v.w * INV_SR;
        }
#pragma unroll
        for (int i = 0; i < VPT; ++i) tsum += (double)st[i];
    }

    // ---- block exclusive scan of per-thread sums
    double inc = tsum;
#pragma unroll
    for (int off = 1; off < 64; off <<= 1) {
        double n = __shfl_up(inc, off, 64);
        if (lane >= off) inc += n;
    }
    if (lane == 63) ws[wid] = inc;
    __syncthreads();

    double chunkpref = rs[0] + rs[1] + rs[2] + rs[3];
    double run = (double)phase_state[row] + chunkpref + (inc - tsum);
#pragma unroll
    for (int w = 0; w < THREADS / 64; ++w)
        if (w < wid) run += ws[w];

    // next_state: unwrapped final phase, written by the last chunk's thread 0
    if (chunk == NCHUNK - 1 && threadIdx.x == 0) {
        next_state[row] = (float)((double)phase_state[row] + chunkpref
                                  + ws[0] + ws[1] + ws[2] + ws[3]);
    }

    // ---- load oq
    float o[VPT];
    {
        const float4* ob = (const float4*)(oq + base_idx);
#pragma unroll
        for (int j = 0; j < VPT / 4; ++j) {
            float4 v = ob[j];
            o[4 * j + 0] = v.x; o[4 * j + 1] = v.y;
            o[4 * j + 2] = v.z; o[4 * j + 3] = v.w;
        }
    }

    // ---- accumulate + pulse; one v_cos per element, arg in revolutions
    float outv[VPT];
#pragma unroll
    for (int i = 0; i < VPT; ++i) {
        run += (double)st[i];
        float ph  = (float)(run - floor(run));     // wrapped phase in [0,1)
        float oqv = o[i];
        float tp  = oqv * 0.66f;
        float tn  = oqv - tp;
        bool  is_rise  = ph < tp;
        bool  in_pulse = ph < oqv;
        float num = is_rise ? ph : (ph - tp);
        float den = is_rise ? (tp + 1e-6f) : (2.0f * tn + 1e-6f);
        // cos(pi * num/den) == v_cos(0.5 * num/den revolutions)
        float rev = 0.5f * num * __builtin_amdgcn_rcpf(den);
        float c   = __builtin_amdgcn_cosf(rev);
        outv[i] = is_rise ? 0.5f * (1.0f - c) : (in_pulse ? c : 0.0f);
    }

    float4* wb = (float4*)(wav + base_idx);
#pragma unroll
    for (int j = 0; j < VPT / 4; ++j) {
        wb[j] = make_float4(outv[4 * j + 0], outv[4 * j + 1],
                            outv[4 * j + 2], outv[4 * j + 3]);
    }
}

extern "C" void kernel_launch(void* const* d_in, const int* in_sizes, int n_in,
                              void* d_out, int out_size, void* d_ws, size_t ws_size,
                              hipStream_t stream)
{
    const float* f0          = (const float*)d_in[0];
    const float* oq          = (const float*)d_in[1];
    const float* phase_state = (const float*)d_in[2];
    float* out = (float*)d_out;                 // [B*T] wav, then [B] next_state

    double* partial = (double*)d_ws;            // B*NCHUNK doubles (32 KB)

    dim3 grid(NCHUNK, BATCH);
    k_chunk_sums<<<grid, THREADS, 0, stream>>>(f0, partial);
    k_emit<<<grid, THREADS, 0, stream>>>(f0, oq, partial, phase_state,
                                         out, out + (size_t)BATCH * T);
}